// Round 1
// baseline (237.512 us; speedup 1.0000x reference)
//
#include <hip/hip_runtime.h>

// PolicyEncoder: out[n,:] = bias + w_state0[obs0[n]] + w_state1[obs1[n]]
//                          + w_act0[act0[n]] + w_act1[act1[n]]
// N = 262144 rows, D = 128 fp32. Latency-bound random gather + streaming write.
//
// R3: force full memory-level parallelism.
//   Evidence: R2 compiled to VGPR_Count=24 — too few registers to hold the
//   8 intended in-flight v4f gathers (needs 32 just for destinations), so the
//   compiler had serialized them into ~4-deep MLP; HBM BW stuck at 42% of peak
//   with VALUBusy 8% (latency-bound, not BW-bound).
//   Fix: sched_barrier(0) between the gather-issue block and the accumulate,
//   so all 8 gathers must be issued (dest regs live) before any math.
//   Also: 32-bit byte offsets (idx<<9, max table 51.2 MB fits) to get the
//   saddr global_load form and cut address VALU/VGPR overhead.
//   Staying at 2 rows/thread keeps VGPRs <= 64 -> 8 waves/SIMD occupancy
//   (the 64-VGPR cliff); 4 rows would halve occupancy for no net MLP gain.

#define PE_N 262144
#define PE_D 128
#define ROWS_PER_BLOCK 16   // 8 row-slots * 2 rows per thread

typedef float v4f __attribute__((ext_vector_type(4)));

__global__ __launch_bounds__(256) void PolicyEncoder_79044578116211_kernel(
    const int* __restrict__ obs0, const int* __restrict__ obs1,
    const int* __restrict__ act0, const int* __restrict__ act1,
    const float* __restrict__ w_state0, const float* __restrict__ w_state1,
    const float* __restrict__ w_act0, const float* __restrict__ w_act1,
    const float* __restrict__ bias, float* __restrict__ out)
{
    const int t    = threadIdx.x;
    const int slot = t >> 5;          // 0..7 : which row-slot in the block
    const int lane = t & 31;          // float4 index within a 128-float row

    const int rowA = blockIdx.x * ROWS_PER_BLOCK + slot;
    const int rowB = rowA + 8;

    // 8 independent index loads (lanes within a slot broadcast from cache).
    const int iA0 = obs0[rowA], iB0 = obs0[rowB];
    const int iA1 = obs1[rowA], iB1 = obs1[rowB];
    const int aA0 = act0[rowA], aB0 = act0[rowB];
    const int aA1 = act1[rowA], aB1 = act1[rowB];

    const unsigned lofs = (unsigned)lane * 16u;   // byte offset within row

    // Bias (L1-resident after first wave).
    v4f xb = *(const v4f*)((const char*)bias + lofs);

    // 8 independent gathers. 32-bit row byte offsets: idx*512B, max 51.2MB.
    v4f A0 = *(const v4f*)((const char*)w_state0 + (((unsigned)iA0) << 9) + lofs);
    v4f A1 = *(const v4f*)((const char*)w_state1 + (((unsigned)iA1) << 9) + lofs);
    v4f A2 = *(const v4f*)((const char*)w_act0   + (((unsigned)aA0) << 9) + lofs);
    v4f A3 = *(const v4f*)((const char*)w_act1   + (((unsigned)aA1) << 9) + lofs);
    v4f B0 = *(const v4f*)((const char*)w_state0 + (((unsigned)iB0) << 9) + lofs);
    v4f B1 = *(const v4f*)((const char*)w_state1 + (((unsigned)iB1) << 9) + lofs);
    v4f B2 = *(const v4f*)((const char*)w_act0   + (((unsigned)aB0) << 9) + lofs);
    v4f B3 = *(const v4f*)((const char*)w_act1   + (((unsigned)aB1) << 9) + lofs);

    // Hard scheduling fence: nothing crosses. All 8 gathers are issued and
    // their destination registers stay live before any accumulation below.
    __builtin_amdgcn_sched_barrier(0);

    v4f accA = (xb + A0) + (A1 + A2) + A3;
    v4f accB = (xb + B0) + (B1 + B2) + B3;

    // Streaming writes: non-temporal so output doesn't evict table rows.
    v4f* outA = (v4f*)((char*)out + (size_t)rowA * (PE_D * 4) + lofs);
    v4f* outB = (v4f*)((char*)out + (size_t)rowB * (PE_D * 4) + lofs);
    __builtin_nontemporal_store(accA, outA);
    __builtin_nontemporal_store(accB, outB);
}

extern "C" void kernel_launch(void* const* d_in, const int* in_sizes, int n_in,
                              void* d_out, int out_size, void* d_ws, size_t ws_size,
                              hipStream_t stream) {
    const int*   obs0     = (const int*)  d_in[0];
    const int*   obs1     = (const int*)  d_in[1];
    const int*   act0     = (const int*)  d_in[2];
    const int*   act1     = (const int*)  d_in[3];
    const float* w_state0 = (const float*)d_in[4];
    const float* w_state1 = (const float*)d_in[5];
    const float* w_act0   = (const float*)d_in[6];
    const float* w_act1   = (const float*)d_in[7];
    const float* bias     = (const float*)d_in[8];
    float*       out      = (float*)d_out;

    const int grid = PE_N / ROWS_PER_BLOCK;  // 16384 blocks
    PolicyEncoder_79044578116211_kernel<<<grid, 256, 0, stream>>>(
        obs0, obs1, act0, act1, w_state0, w_state1, w_act0, w_act1, bias, out);
}